// Round 3
// baseline (75.708 us; speedup 1.0000x reference)
//
#include <hip/hip_runtime.h>

// KA-conv: out[b,o,h,w] = sum_m P_om(v) / (1+|Q_om(v)|), v = zero-padded patch
// value, m = c*9+ki*3+kj, M=144. ~75.5M rational evals, pure fp32 VALU.
//
// R2/R3 changes vs R1 (latency-bound at 49% VALUBusy, 17% occupancy):
//  - coefficients for the block's output channel staged in LDS (5.76 KB);
//    inner loop reads are broadcast ds_read with immediate offsets instead of
//    per-m s_load chains (the ~150cyc/m stall that matched VALUBusy~49%).
//  - 2 rows/thread (was 4) -> grid 1024 blocks -> 4 blocks/CU -> 4 waves/SIMD.
//  - c-loop unrolled x2 with ping-pong patch buffers: software pipeline with
//    zero register-copy overhead (R2 had a 12 v_mov/iter X=Xn shuffle).

constexpr int Bn = 4, Cin = 16, Hh = 64, Ww = 64, Oc = 32, Mtot = 144;

__global__ __launch_bounds__(256, 4)
void ka_conv_kernel(const float* __restrict__ x,
                    const float* __restrict__ nums,
                    const float* __restrict__ denoms,
                    float* __restrict__ out) {
  __shared__ float sA[Mtot * 6];   // numerator coeffs a0..a5 per m
  __shared__ float sB[Mtot * 4];   // denominator coeffs b1..b4 per m

  const int tid = threadIdx.x;
  int blk = blockIdx.x;
  const int ht = blk & 7;  blk >>= 3;   // 8 height tiles of 8 rows
  const int o  = blk & 31; blk >>= 5;   // output channel
  const int b  = blk;                   // batch

  // Stage this channel's coefficients into LDS (one-time, coalesced).
  {
    const float* __restrict__ an = nums   + (size_t)o * Mtot * 6;
    const float* __restrict__ bd = denoms + (size_t)o * Mtot * 4;
    for (int i = tid; i < Mtot * 6; i += 256) sA[i] = an[i];
    for (int i = tid; i < Mtot * 4; i += 256) sB[i] = bd[i];
  }
  __syncthreads();

  const int w  = tid & 63;           // output column (lane -> coalesced)
  const int rg = tid >> 6;           // rowgroup 0..3
  const int h0 = ht * 8 + rg * 2;    // this thread's 2 output rows: h0, h0+1

  float acc0 = 0.f, acc1 = 0.f;

  const float* __restrict__ xb = x + (size_t)b * Cin * Hh * Ww;

  // ---- patch loader: rows h0-1..h0+2, cols w-1..w+1, zero outside ----
  auto load_patch = [&](int c, float X[4][3]) {
    const float* __restrict__ xc = xb + (size_t)c * (Hh * Ww);
    #pragma unroll
    for (int i = 0; i < 4; ++i) {
      const int  hr  = h0 - 1 + i;
      const int  hc  = min(max(hr, 0), Hh - 1);
      const bool hin = (unsigned)hr < (unsigned)Hh;
      #pragma unroll
      for (int j = 0; j < 3; ++j) {
        const int  wc  = w - 1 + j;
        const int  wcc = min(max(wc, 0), Ww - 1);
        const bool win = (unsigned)wc < (unsigned)Ww;
        const float v  = xc[hc * Ww + wcc];
        X[i][j] = (hin && win) ? v : 0.f;
      }
    }
  };

  // ---- rational-conv accumulation for one input channel ----
  auto compute = [&](int c, const float X[4][3]) {
    const int mbase = c * 9;
    #pragma unroll
    for (int ki = 0; ki < 3; ++ki) {
      #pragma unroll
      for (int kj = 0; kj < 3; ++kj) {
        const int m = mbase + ki * 3 + kj;
        // broadcast LDS reads; address = VGPR base (from c) + imm offset
        const float a0 = sA[m * 6 + 0], a1 = sA[m * 6 + 1], a2 = sA[m * 6 + 2];
        const float a3 = sA[m * 6 + 3], a4 = sA[m * 6 + 4], a5 = sA[m * 6 + 5];
        const float b1 = sB[m * 4 + 0], b2 = sB[m * 4 + 1];
        const float b3 = sB[m * 4 + 2], b4 = sB[m * 4 + 3];
        #pragma unroll
        for (int p = 0; p < 2; ++p) {
          const float v = X[p + ki][kj];
          // P(v) Horner
          float num = fmaf(fmaf(fmaf(fmaf(fmaf(a5, v, a4), v, a3), v, a2), v, a1), v, a0);
          // Q(v) = 1 + |v*(b1 + v*(b2 + v*(b3 + v*b4)))|
          float dp  = fmaf(fmaf(fmaf(b4, v, b3), v, b2), v, b1) * v;
          float den = 1.0f + fabsf(dp);
          float r   = __builtin_amdgcn_rcpf(den);   // v_rcp_f32
          if (p == 0) acc0 = fmaf(num, r, acc0);
          else        acc1 = fmaf(num, r, acc1);
        }
      }
    }
  };

  // ---- software-pipelined c-loop, unroll x2, ping-pong buffers ----
  float X0[4][3], X1[4][3];
  load_patch(0, X0);
  for (int c = 0; c < Cin; c += 2) {
    load_patch(c + 1, X1);          // Cin even: c+1 always valid
    compute(c, X0);
    if (c + 2 < Cin) load_patch(c + 2, X0);
    compute(c + 1, X1);
  }

  float* op = out + ((size_t)(b * Oc + o) * Hh + h0) * Ww + w;
  op[0]  = acc0;
  op[Ww] = acc1;
}

extern "C" void kernel_launch(void* const* d_in, const int* in_sizes, int n_in,
                              void* d_out, int out_size, void* d_ws, size_t ws_size,
                              hipStream_t stream) {
  const float* x      = (const float*)d_in[0];
  const float* nums   = (const float*)d_in[1];
  const float* denoms = (const float*)d_in[2];
  float* out          = (float*)d_out;
  // blockIdx = ((b*32 + o)*8 + ht)
  dim3 grid(Bn * Oc * 8);
  ka_conv_kernel<<<grid, 256, 0, stream>>>(x, nums, denoms, out);
}

// Round 4
// 34.620 us; speedup vs baseline: 2.1868x; 2.1868x over previous
//
#include <hip/hip_runtime.h>

// KA-conv: out[b,o,h,w] = sum_m P_om(v) / (1+|Q_om(v)|), v = zero-padded patch
// value, m = c*9+ki*3+kj, M=144. ~75.5M rational evals, pure fp32 VALU.
//
// R4: R3 regressed (81us) because float X[4][3] passed through lambda pointer
// params went to SCRATCH (WRITE_SIZE 91MB vs 2MB ideal — classic rule-#20
// spill). This version has NO arrays and NO lambdas: the 6x3 patch window is
// 12 named scalar registers; taps are a macro with compile-time LDS offsets.
// Keeps: LDS-staged coefficients (5.76KB/block, broadcast ds_read), 2 rows/
// thread, grid 1024 (4 blocks/CU). #pragma unroll 2 lets the compiler
// pipeline next-channel global loads under current-channel VALU itself.

constexpr int Bn = 4, Cin = 16, Hh = 64, Ww = 64, Oc = 32, Mtot = 144;

__global__ __launch_bounds__(256, 4)
void ka_conv_kernel(const float* __restrict__ x,
                    const float* __restrict__ nums,
                    const float* __restrict__ denoms,
                    float* __restrict__ out) {
  __shared__ float sA[Mtot * 6];   // numerator coeffs a0..a5 per m
  __shared__ float sB[Mtot * 4];   // denominator coeffs b1..b4 per m

  const int tid = threadIdx.x;
  int blk = blockIdx.x;
  const int ht = blk & 7;  blk >>= 3;   // 8 height tiles of 8 rows
  const int o  = blk & 31; blk >>= 5;   // output channel
  const int b  = blk;                   // batch

  {  // stage this channel's coefficients into LDS (coalesced, once)
    const float* __restrict__ an = nums   + (size_t)o * Mtot * 6;
    const float* __restrict__ bd = denoms + (size_t)o * Mtot * 4;
    for (int i = tid; i < Mtot * 6; i += 256) sA[i] = an[i];
    for (int i = tid; i < Mtot * 4; i += 256) sB[i] = bd[i];
  }
  __syncthreads();

  const int w  = tid & 63;           // output column (lane -> coalesced)
  const int rg = tid >> 6;           // rowgroup 0..3
  const int h0 = ht * 8 + rg * 2;    // this thread's 2 output rows: h0, h0+1

  // clamped neighbor columns + validity masks (loop-invariant)
  const int  wm   = max(w - 1, 0), wp = min(w + 1, Ww - 1);
  const bool wl   = (w - 1) >= 0;
  const bool wr   = (w + 1) < Ww;
  const int  h_1  = max(h0 - 1, 0);        // top halo row (clamped)
  const int  h2c  = min(h0 + 2, Hh - 1);   // bottom halo row (clamped)
  const bool htv  = (h0 - 1) >= 0;
  const bool hbv  = (h0 + 2) < Hh;
  const bool tl = htv && wl, tr_ = htv && wr;   // corner masks
  const bool bl = hbv && wl, br = hbv && wr;

  float acc0 = 0.f, acc1 = 0.f;
  const float* __restrict__ xb = x + (size_t)b * Cin * Hh * Ww;

  // one tap: coeff slot t (0..8) of channel c, top value vt -> acc0,
  // bottom value vb -> acc1. LDS offsets are compile-time per t.
#define EVAL(t, vt, vb) do {                                                   \
    const float a0 = pa[(t)*6 + 0], a1 = pa[(t)*6 + 1], a2 = pa[(t)*6 + 2];    \
    const float a3 = pa[(t)*6 + 3], a4 = pa[(t)*6 + 4], a5 = pa[(t)*6 + 5];    \
    const float c1 = pb[(t)*4 + 0], c2 = pb[(t)*4 + 1];                        \
    const float c3 = pb[(t)*4 + 2], c4 = pb[(t)*4 + 3];                        \
    {                                                                          \
      const float v  = (vt);                                                   \
      float num = fmaf(fmaf(fmaf(fmaf(fmaf(a5,v,a4),v,a3),v,a2),v,a1),v,a0);   \
      float dp  = fmaf(fmaf(fmaf(c4,v,c3),v,c2),v,c1) * v;                     \
      float r   = __builtin_amdgcn_rcpf(1.0f + fabsf(dp));                     \
      acc0 = fmaf(num, r, acc0);                                               \
    }                                                                          \
    {                                                                          \
      const float v  = (vb);                                                   \
      float num = fmaf(fmaf(fmaf(fmaf(fmaf(a5,v,a4),v,a3),v,a2),v,a1),v,a0);   \
      float dp  = fmaf(fmaf(fmaf(c4,v,c3),v,c2),v,c1) * v;                     \
      float r   = __builtin_amdgcn_rcpf(1.0f + fabsf(dp));                     \
      acc1 = fmaf(num, r, acc1);                                               \
    }                                                                          \
  } while (0)

  #pragma unroll 2
  for (int c = 0; c < Cin; ++c) {
    const float* __restrict__ xc = xb + (size_t)c * (Hh * Ww);
    const float* __restrict__ r0 = xc + h_1 * Ww;         // h0-1 (clamped)
    const float* __restrict__ r1 = xc + h0 * Ww;          // h0
    const float* __restrict__ r2 = xc + (h0 + 1) * Ww;    // h0+1
    const float* __restrict__ r3 = xc + h2c * Ww;         // h0+2 (clamped)

    // 12 unconditional coalesced loads, then mask halo lanes to zero
    float v00 = r0[wm], v01 = r0[w], v02 = r0[wp];
    float v10 = r1[wm], v11 = r1[w], v12 = r1[wp];
    float v20 = r2[wm], v21 = r2[w], v22 = r2[wp];
    float v30 = r3[wm], v31 = r3[w], v32 = r3[wp];
    v00 = tl  ? v00 : 0.f;  v01 = htv ? v01 : 0.f;  v02 = tr_ ? v02 : 0.f;
    v10 = wl  ? v10 : 0.f;                          v12 = wr  ? v12 : 0.f;
    v20 = wl  ? v20 : 0.f;                          v22 = wr  ? v22 : 0.f;
    v30 = bl  ? v30 : 0.f;  v31 = hbv ? v31 : 0.f;  v32 = br  ? v32 : 0.f;

    const float* __restrict__ pa = sA + c * 54;   // 9 taps * 6 coeffs
    const float* __restrict__ pb = sB + c * 36;   // 9 taps * 4 coeffs
    // ki=0 uses rows (h0-1, h0); ki=1 rows (h0, h0+1); ki=2 rows (h0+1, h0+2)
    EVAL(0, v00, v10);  EVAL(1, v01, v11);  EVAL(2, v02, v12);
    EVAL(3, v10, v20);  EVAL(4, v11, v21);  EVAL(5, v12, v22);
    EVAL(6, v20, v30);  EVAL(7, v21, v31);  EVAL(8, v22, v32);
  }
#undef EVAL

  float* op = out + ((size_t)(b * Oc + o) * Hh + h0) * Ww + w;
  op[0]  = acc0;
  op[Ww] = acc1;
}

extern "C" void kernel_launch(void* const* d_in, const int* in_sizes, int n_in,
                              void* d_out, int out_size, void* d_ws, size_t ws_size,
                              hipStream_t stream) {
  const float* x      = (const float*)d_in[0];
  const float* nums   = (const float*)d_in[1];
  const float* denoms = (const float*)d_in[2];
  float* out          = (float*)d_out;
  // blockIdx = ((b*32 + o)*8 + ht)
  dim3 grid(Bn * Oc * 8);
  ka_conv_kernel<<<grid, 256, 0, stream>>>(x, nums, denoms, out);
}

// Round 5
// 33.840 us; speedup vs baseline: 2.2372x; 1.0230x over previous
//
#include <hip/hip_runtime.h>

// KA-conv: out[b,o,h,w] = sum_m P_om(v) / (1+|Q_om(v)|), v = zero-padded patch
// value, m = c*9+ki*3+kj, M=144. ~75.5M rational evals, pure fp32 VALU.
//
// R5: R4 was LDS-issue-pipe bound (27 ds_read/c-iter/wave for coefficients;
// LDS demand ~2.3x VALU demand -> VALUBusy 54%, 41us, matching model).
// Coefficients are wave-uniform (o from blockIdx, c/t compile-time), so this
// version reads them as plain global loads -> compiler scalarizes to s_load
// on the SMEM pipe (R1 evidence: SGPR=112). SMEM demand ~48 instr/c-iter/CU
// << VALU. No LDS at all. Geometry kept from R4: 2 rows/thread, 256-thread
// blocks, grid 1024 = 4 blocks/CU = 16 waves/CU (2x R1's occupancy, which is
// what R1's s_load latency needed).

constexpr int Bn = 4, Cin = 16, Hh = 64, Ww = 64, Oc = 32, Mtot = 144;

__global__ __launch_bounds__(256, 4)
void ka_conv_kernel(const float* __restrict__ x,
                    const float* __restrict__ nums,
                    const float* __restrict__ denoms,
                    float* __restrict__ out) {
  const int tid = threadIdx.x;
  int blk = blockIdx.x;
  const int ht = blk & 7;  blk >>= 3;   // 8 height tiles of 8 rows
  const int o  = blk & 31; blk >>= 5;   // output channel
  const int b  = blk;                   // batch

  const int w  = tid & 63;           // output column (lane -> coalesced)
  const int rg = tid >> 6;           // rowgroup 0..3
  const int h0 = ht * 8 + rg * 2;    // this thread's 2 output rows: h0, h0+1

  // clamped neighbor columns + validity masks (loop-invariant)
  const int  wm   = max(w - 1, 0), wp = min(w + 1, Ww - 1);
  const bool wl   = (w - 1) >= 0;
  const bool wr   = (w + 1) < Ww;
  const int  h_1  = max(h0 - 1, 0);        // top halo row (clamped)
  const int  h2c  = min(h0 + 2, Hh - 1);   // bottom halo row (clamped)
  const bool htv  = (h0 - 1) >= 0;
  const bool hbv  = (h0 + 2) < Hh;
  const bool tl = htv && wl, tr_ = htv && wr;   // corner masks
  const bool bl = hbv && wl, br = hbv && wr;

  float acc0 = 0.f, acc1 = 0.f;
  const float* __restrict__ xb = x + (size_t)b * Cin * Hh * Ww;

  // base pointers for this output channel's coefficients (wave-uniform)
  const float* __restrict__ anum = nums   + (size_t)o * Mtot * 6;
  const float* __restrict__ bden = denoms + (size_t)o * Mtot * 4;

  // one tap: coeff slot t (0..8) of channel c; vt -> acc0 (row h0),
  // vb -> acc1 (row h0+1). pa/pb are uniform -> s_load with imm offsets.
#define TAP(t, vt, vb) do {                                                    \
    const float a0 = pa[(t)*6 + 0], a1 = pa[(t)*6 + 1], a2 = pa[(t)*6 + 2];    \
    const float a3 = pa[(t)*6 + 3], a4 = pa[(t)*6 + 4], a5 = pa[(t)*6 + 5];    \
    const float c1 = pb[(t)*4 + 0], c2 = pb[(t)*4 + 1];                        \
    const float c3 = pb[(t)*4 + 2], c4 = pb[(t)*4 + 3];                        \
    {                                                                          \
      const float v  = (vt);                                                   \
      float num = fmaf(fmaf(fmaf(fmaf(fmaf(a5,v,a4),v,a3),v,a2),v,a1),v,a0);   \
      float dp  = fmaf(fmaf(fmaf(c4,v,c3),v,c2),v,c1) * v;                     \
      float r   = __builtin_amdgcn_rcpf(1.0f + fabsf(dp));                     \
      acc0 = fmaf(num, r, acc0);                                               \
    }                                                                          \
    {                                                                          \
      const float v  = (vb);                                                   \
      float num = fmaf(fmaf(fmaf(fmaf(fmaf(a5,v,a4),v,a3),v,a2),v,a1),v,a0);   \
      float dp  = fmaf(fmaf(fmaf(c4,v,c3),v,c2),v,c1) * v;                     \
      float r   = __builtin_amdgcn_rcpf(1.0f + fabsf(dp));                     \
      acc1 = fmaf(num, r, acc1);                                               \
    }                                                                          \
  } while (0)

  #pragma unroll 2
  for (int c = 0; c < Cin; ++c) {
    const float* __restrict__ xc = xb + (size_t)c * (Hh * Ww);
    const float* __restrict__ r0 = xc + h_1 * Ww;         // h0-1 (clamped)
    const float* __restrict__ r1 = xc + h0 * Ww;          // h0
    const float* __restrict__ r2 = xc + (h0 + 1) * Ww;    // h0+1
    const float* __restrict__ r3 = xc + h2c * Ww;         // h0+2 (clamped)

    // 12 unconditional coalesced loads, then mask halo lanes to zero
    float v00 = r0[wm], v01 = r0[w], v02 = r0[wp];
    float v10 = r1[wm], v11 = r1[w], v12 = r1[wp];
    float v20 = r2[wm], v21 = r2[w], v22 = r2[wp];
    float v30 = r3[wm], v31 = r3[w], v32 = r3[wp];
    v00 = tl  ? v00 : 0.f;  v01 = htv ? v01 : 0.f;  v02 = tr_ ? v02 : 0.f;
    v10 = wl  ? v10 : 0.f;                          v12 = wr  ? v12 : 0.f;
    v20 = wl  ? v20 : 0.f;                          v22 = wr  ? v22 : 0.f;
    v30 = bl  ? v30 : 0.f;  v31 = hbv ? v31 : 0.f;  v32 = br  ? v32 : 0.f;

    const float* __restrict__ pa = anum + c * 54;   // 9 taps * 6 coeffs
    const float* __restrict__ pb = bden + c * 36;   // 9 taps * 4 coeffs
    // ki=0 uses rows (h0-1, h0); ki=1 rows (h0, h0+1); ki=2 rows (h0+1, h0+2)
    TAP(0, v00, v10);  TAP(1, v01, v11);  TAP(2, v02, v12);
    TAP(3, v10, v20);  TAP(4, v11, v21);  TAP(5, v12, v22);
    TAP(6, v20, v30);  TAP(7, v21, v31);  TAP(8, v22, v32);
  }
#undef TAP

  float* op = out + ((size_t)(b * Oc + o) * Hh + h0) * Ww + w;
  op[0]  = acc0;
  op[Ww] = acc1;
}

extern "C" void kernel_launch(void* const* d_in, const int* in_sizes, int n_in,
                              void* d_out, int out_size, void* d_ws, size_t ws_size,
                              hipStream_t stream) {
  const float* x      = (const float*)d_in[0];
  const float* nums   = (const float*)d_in[1];
  const float* denoms = (const float*)d_in[2];
  float* out          = (float*)d_out;
  // blockIdx = ((b*32 + o)*8 + ht)
  dim3 grid(Bn * Oc * 8);
  ka_conv_kernel<<<grid, 256, 0, stream>>>(x, nums, denoms, out);
}